// Round 10
// baseline (39.098 us; speedup 1.0000x reference)
//
#include <hip/hip_runtime.h>
#include <math.h>

// Problem constants (from reference)
#define BATCH 128
#define LL    4096
#define DIM   64
#define EPS   1e-3f
#define LUTN  2048

#define LOG2E 1.44269504088896340736f
#define LN2   0.69314718055994530942f

// Taylor coefficients of s(z) = (exp2(z)-1-ln2*z)/z^2  (z in [-1, 0])
#define GC2 0.2402265069591007f     // ln2^2/2
#define GC3 0.05550410866482158f    // ln2^3/6
#define GC4 0.009618129107628477f   // ln2^4/24
#define GC5 0.0013333558146428443f  // ln2^5/120

// d_ws layout (floats):
//  [0    .. 1536) : T[j][48], j = channel-pair 0..31; per j, br = 0..2 at f32x2
//                   offset br*8: {T0',..,T4', B', Fw, pad}. T' = 2*tap
//                   (log2e-scaled), B' = bias - sum(tap)  (2x-1 folded).
//  [1536 .. 1560) : LIN[3][8] = {L0..L4, Lb, pad, pad} per branch, folded:
//                   Lk = 2*ln2*r_k, Lb = ln2*(rb - sum r_k)
//  [1560 .. 1563) : FB[3]  = f_b
//  [1563 .. 1565) : D0, D1
//  [1565]         : invh ; [1566] : nlo ; [1567] : lo
//  [1568 .. 1568+4*LUTN) : LUT float4 {F0(e_i), F1(e_i), dF0_i, dF1_i}

typedef float f32x2 __attribute__((ext_vector_type(2)));

__device__ __forceinline__ f32x2 pk_fma(f32x2 a, f32x2 b, f32x2 c) {
    return __builtin_elementwise_fma(a, b, c);
}

__device__ __forceinline__ float elu_plain(float z) {
    return z > 0.0f ? z : (__expf(z) - 1.0f);
}

// ONE prologue kernel, 8 blocks x 256 threads.
__global__ __launch_bounds__(256) void enc_prep(
    const float* __restrict__ cw0, const float* __restrict__ cb0, const float* __restrict__ cg0,
    const float* __restrict__ cbe0, const float* __restrict__ cm0, const float* __restrict__ cv0,
    const float* __restrict__ cw1, const float* __restrict__ cb1, const float* __restrict__ cg1,
    const float* __restrict__ cbe1, const float* __restrict__ cm1, const float* __restrict__ cv1,
    const float* __restrict__ cw2, const float* __restrict__ cb2, const float* __restrict__ cg2,
    const float* __restrict__ cbe2, const float* __restrict__ cm2, const float* __restrict__ cv2,
    const float* __restrict__ f0w, const float* __restrict__ f0b,
    const float* __restrict__ f1w, const float* __restrict__ f1b,
    const float* __restrict__ f2w, const float* __restrict__ f2b,
    const float* __restrict__ mpw, const float* __restrict__ mpb, const float* __restrict__ mpg,
    const float* __restrict__ mpbe, const float* __restrict__ mpm, const float* __restrict__ mpv,
    const float* __restrict__ mdw, const float* __restrict__ mdb, const float* __restrict__ mdg,
    const float* __restrict__ mdbe, const float* __restrict__ mdm, const float* __restrict__ mdv,
    float* __restrict__ W)
{
    const int t   = threadIdx.x;
    const int blk = blockIdx.x;
    __shared__ float smod[64][4];          // {A, C, m0, m1}
    __shared__ float s_lo[3], s_hi[3];
    __shared__ float sD[2];
    __shared__ float srange[2];            // lo, hstep

    if (t < 192) {
        const int br = t >> 6;             // wave-aligned: wave 0,1,2 = branch 0,1,2
        const int d  = t & 63;
        const float* cw  = (br == 0) ? cw0  : (br == 1) ? cw1  : cw2;
        const float* cb  = (br == 0) ? cb0  : (br == 1) ? cb1  : cb2;
        const float* cg  = (br == 0) ? cg0  : (br == 1) ? cg1  : cg2;
        const float* cbe = (br == 0) ? cbe0 : (br == 1) ? cbe1 : cbe2;
        const float* cm  = (br == 0) ? cm0  : (br == 1) ? cm1  : cm2;
        const float* cv  = (br == 0) ? cv0  : (br == 1) ? cv1  : cv2;
        const float* fw  = (br == 0) ? f0w  : (br == 1) ? f1w  : f2w;
        const float s = cg[d] / sqrtf(cv[d] + EPS);
        float tap[5], habs = 0.0f, tsum = 0.0f;
        #pragma unroll
        for (int k = 0; k < 5; ++k) {
            tap[k] = cw[k * 64 + d] * s * LOG2E;
            habs += fabsf(tap[k]);
            tsum += tap[k];
        }
        const float bias = ((cb[d] - cm[d]) * s + cbe[d]) * LOG2E;
        const float fwd  = fw[d];
        if (blk == 0) {
            // f32x2 layout: j*24 + br*8 + {0..4 taps, 5 bias, 6 fw, 7 pad}
            float* o = W + ((d >> 1) * 24 + br * 8) * 2 + (d & 1);
            o[0] = 2.0f * tap[0]; o[2] = 2.0f * tap[1]; o[4] = 2.0f * tap[2];
            o[6] = 2.0f * tap[3]; o[8] = 2.0f * tap[4];
            o[10] = bias - tsum;           // (2x-1) folded
            o[12] = fwd;
        }
        const float hb = LN2 * (habs + fabsf(bias));   // bound on |h_real|, |x~|<=1
        // reductions over the 64-lane branch wave:
        float r0 = fwd * tap[0], r1 = fwd * tap[1], r2 = fwd * tap[2];
        float r3 = fwd * tap[3], r4 = fwd * tap[4], rb = fwd * bias;
        float myS = fabsf(fwd) * fmaxf(1.0f, hb);      // |fw * elu(h)| bound
        #pragma unroll
        for (int off = 32; off; off >>= 1) {
            r0 += __shfl_down(r0, off);
            r1 += __shfl_down(r1, off);
            r2 += __shfl_down(r2, off);
            r3 += __shfl_down(r3, off);
            r4 += __shfl_down(r4, off);
            rb += __shfl_down(rb, off);
            myS += __shfl_down(myS, off);
        }
        if ((t & 63) == 0) {
            const float fb = ((br == 0) ? f0b : (br == 1) ? f1b : f2b)[0];
            s_lo[br] = fb - myS;
            s_hi[br] = fb + myS;
            if (blk == 0) {
                float* Lb = W + 1536 + br * 8;
                const float rs = r0 + r1 + r2 + r3 + r4;
                Lb[0] = 2.0f * LN2 * r0; Lb[1] = 2.0f * LN2 * r1;
                Lb[2] = 2.0f * LN2 * r2; Lb[3] = 2.0f * LN2 * r3;
                Lb[4] = 2.0f * LN2 * r4;
                Lb[5] = LN2 * (rb - rs);   // (2x-1) folded
                W[1560 + br] = fb;
            }
        }
    } else {
        const int d = t - 192;
        const float smp = mpg[d] / sqrtf(mpv[d] + EPS);
        const float A = mpw[d] * smp;
        const float C = (mpb[d] - mpm[d]) * smp + mpbe[d];
        const float s0 = mdg[0] / sqrtf(mdv[0] + EPS);
        const float s1 = mdg[1] / sqrtf(mdv[1] + EPS);
        smod[d][0] = A;
        smod[d][1] = C;
        smod[d][2] = mdw[d * 2 + 0] * s0;
        smod[d][3] = mdw[d * 2 + 1] * s1;
        if (d == 0) {
            const float D0 = (mdb[0] - mdm[0]) * s0 + mdbe[0];
            const float D1 = (mdb[1] - mdm[1]) * s1 + mdbe[1];
            sD[0] = D0; sD[1] = D1;
            if (blk == 0) { W[1563] = D0; W[1564] = D1; }
        }
    }
    __syncthreads();

    if (t == 0) {
        float lo = fminf(s_lo[0], fminf(s_lo[1], s_lo[2]));
        float hi = fmaxf(s_hi[0], fmaxf(s_hi[1], s_hi[2]));
        float pad = 1e-3f * (hi - lo) + 1e-6f;
        lo -= pad; hi += pad;
        srange[0] = lo;
        srange[1] = (hi - lo) / (float)(LUTN - 1);
        if (blk == 0) {
            const float invh = (float)(LUTN - 1) / (hi - lo);
            W[1565] = invh;
            W[1566] = -lo * invh;
            W[1567] = lo;
        }
    }
    __syncthreads();

    // LUT slice: entry i for this thread
    const int i = blk * 256 + t;
    const float lo = srange[0], hs = srange[1];
    const float D0 = sD[0], D1 = sD[1];
    const float e0 = fmaf((float)i, hs, lo);
    const float e1 = fmaf((float)(i + 1), hs, lo);
    float a0 = D0, a1 = D1, b0 = D0, b1 = D1;
    #pragma unroll 8
    for (int d = 0; d < 64; ++d) {
        const float A = smod[d][0], C = smod[d][1], m0 = smod[d][2], m1 = smod[d][3];
        float u;
        u = elu_plain(fmaf(A, e0, C)); a0 = fmaf(m0, u, a0); a1 = fmaf(m1, u, a1);
        u = elu_plain(fmaf(A, e1, C)); b0 = fmaf(m0, u, b0); b1 = fmaf(m1, u, b1);
    }
    float4* lut = (float4*)(W + 1568);
    lut[i] = make_float4(a0, a1, b0 - a0, b1 - a1);
}

__device__ __forceinline__ float2 lut_eval(float e, float invh, float nlo,
                                           const float4* __restrict__ lut) {
    float tt = fminf(fmaxf(fmaf(e, invh, nlo), 0.0f), (float)(LUTN - 1));
    float fi = floorf(tt); float f = tt - fi;
    float4 v = lut[(int)fi];
    return make_float2(fmaf(f, v.z, v.x), fmaf(f, v.w, v.y));
}

// nonlinear elu remainder: fw * z^2 * s(z), z = min(h',0), deg-3 Taylor tail,
// GC constants live in registers (not the weight stream)
__device__ __forceinline__ void nl_acc(f32x2 h, f32x2 fw, f32x2& e) {
    const f32x2 zero = {0.0f, 0.0f};
    f32x2 z  = __builtin_elementwise_min(h, zero);
    f32x2 zz = z * z;
    f32x2 s  = pk_fma(z, f32x2{GC5, GC5}, f32x2{GC4, GC4});
    s = pk_fma(z, s, f32x2{GC3, GC3});
    s = pk_fma(z, s, f32x2{GC2, GC2});
    e = pk_fma(fw, zz * s, e);
}

// conv chain for one position (offset o into the 8-wide window)
#define CONV(tpb, xa, o) \
    pk_fma(tpb[0], xa[o], pk_fma(tpb[1], xa[o+1], pk_fma(tpb[2], xa[o+2], \
    pk_fma(tpb[3], xa[o+3], pk_fma(tpb[4], xa[o+4], tpb[5])))))

// 512 blocks x 256 threads; 4 positions/thread, channel-pair packed f32 math.
// Weight stream (scalar loads) amortized over 4 positions.
__global__ __launch_bounds__(256) void enc_main(
    const float* __restrict__ x, const int* __restrict__ perm,
    const float* __restrict__ W, float* __restrict__ out)
{
    const int gid = blockIdx.x * 256 + threadIdx.x;   // position-quad index
    const int b   = gid >> 10;
    const int l0  = (gid & 1023) * 4;
    const float* xrow = x + ((size_t)b << 12);
    const int*   prow = perm + ((size_t)b << 12);

    // 8-wide window x[l0-2 .. l0+5] via three aligned 16B loads (no intra-chunk wrap)
    const float4 q0 = *(const float4*)(xrow + ((l0 - 4) & (LL - 1)));
    const float4 q1 = *(const float4*)(xrow + l0);
    const float4 q2 = *(const float4*)(xrow + ((l0 + 4) & (LL - 1)));
    const int4 pq0 = *(const int4*)(prow + ((l0 - 4) & (LL - 1)));
    const int4 pq1 = *(const int4*)(prow + l0);
    const int4 pq2 = *(const int4*)(prow + ((l0 + 4) & (LL - 1)));

    float xw[8], xg[8];
    xw[0] = q0.z; xw[1] = q0.w;
    xw[2] = q1.x; xw[3] = q1.y; xw[4] = q1.z; xw[5] = q1.w;
    xw[6] = q2.x; xw[7] = q2.y;
    xg[0] = xrow[pq0.z]; xg[1] = xrow[pq0.w];
    xg[2] = xrow[pq1.x]; xg[3] = xrow[pq1.y];
    xg[4] = xrow[pq1.z]; xg[5] = xrow[pq1.w];
    xg[6] = xrow[pq2.x]; xg[7] = xrow[pq2.y];

    // collapsed linear part, position-pair packed: pos(0,1) and pos(2,3)
    const float* LA = W + 1536;
    const float* LB = W + 1544;
    const float* LC = W + 1552;
    f32x2 pw0[5], pw2[5], pg0[5], pg2[5];
    #pragma unroll
    for (int k = 0; k < 5; ++k) {
        pw0[k] = f32x2{xw[k],     xw[k + 1]};
        pw2[k] = f32x2{xw[k + 2], xw[k + 3]};
        pg0[k] = f32x2{xg[k],     xg[k + 1]};
        pg2[k] = f32x2{xg[k + 2], xg[k + 3]};
    }
    f32x2 linA01, linA23, linB01, linB23, linC01, linC23;
    {
        f32x2 la[6], lb[6], lc[6];
        #pragma unroll
        for (int k = 0; k < 6; ++k) {
            la[k] = f32x2{LA[k], LA[k]};
            lb[k] = f32x2{LB[k], LB[k]};
            lc[k] = f32x2{LC[k], LC[k]};
        }
        linA01 = pk_fma(la[0], pw0[0], pk_fma(la[1], pw0[1], pk_fma(la[2], pw0[2],
                 pk_fma(la[3], pw0[3], pk_fma(la[4], pw0[4], la[5])))));
        linA23 = pk_fma(la[0], pw2[0], pk_fma(la[1], pw2[1], pk_fma(la[2], pw2[2],
                 pk_fma(la[3], pw2[3], pk_fma(la[4], pw2[4], la[5])))));
        linB01 = pk_fma(lb[0], pw0[0], pk_fma(lb[1], pw0[1], pk_fma(lb[2], pw0[2],
                 pk_fma(lb[3], pw0[3], pk_fma(lb[4], pw0[4], lb[5])))));
        linB23 = pk_fma(lb[0], pw2[0], pk_fma(lb[1], pw2[1], pk_fma(lb[2], pw2[2],
                 pk_fma(lb[3], pw2[3], pk_fma(lb[4], pw2[4], lb[5])))));
        linC01 = pk_fma(lc[0], pg0[0], pk_fma(lc[1], pg0[1], pk_fma(lc[2], pg0[2],
                 pk_fma(lc[3], pg0[3], pk_fma(lc[4], pg0[4], lc[5])))));
        linC23 = pk_fma(lc[0], pg2[0], pk_fma(lc[1], pg2[1], pk_fma(lc[2], pg2[2],
                 pk_fma(lc[3], pg2[3], pk_fma(lc[4], pg2[4], lc[5])))));
    }

    // channel-pair splat windows for the main loop
    f32x2 xs[8], xi[8];
    #pragma unroll
    for (int k = 0; k < 8; ++k) {
        xs[k] = f32x2{xw[k], xw[k]};
        xi[k] = f32x2{xg[k], xg[k]};
    }

    // nonlinear accumulators: [branch][pos], f32x2 over the channel pair
    f32x2 eA0 = {0, 0}, eA1 = {0, 0}, eA2 = {0, 0}, eA3 = {0, 0};
    f32x2 eB0 = {0, 0}, eB1 = {0, 0}, eB2 = {0, 0}, eB3 = {0, 0};
    f32x2 eC0 = {0, 0}, eC1 = {0, 0}, eC2 = {0, 0}, eC3 = {0, 0};

    #pragma unroll 2
    for (int j = 0; j < 32; ++j) {
        const f32x2* tp = (const f32x2*)W + j * 24;
        const f32x2* t0 = tp;          // branch 0: taps 0..4, bias 5, fw 6
        const f32x2* t1 = tp + 8;      // branch 1
        const f32x2* t2 = tp + 16;     // branch 2

        nl_acc(CONV(t0, xs, 0), t0[6], eA0);
        nl_acc(CONV(t0, xs, 1), t0[6], eA1);
        nl_acc(CONV(t0, xs, 2), t0[6], eA2);
        nl_acc(CONV(t0, xs, 3), t0[6], eA3);

        nl_acc(CONV(t1, xs, 0), t1[6], eB0);
        nl_acc(CONV(t1, xs, 1), t1[6], eB1);
        nl_acc(CONV(t1, xs, 2), t1[6], eB2);
        nl_acc(CONV(t1, xs, 3), t1[6], eB3);

        nl_acc(CONV(t2, xi, 0), t2[6], eC0);
        nl_acc(CONV(t2, xi, 1), t2[6], eC1);
        nl_acc(CONV(t2, xi, 2), t2[6], eC2);
        nl_acc(CONV(t2, xi, 3), t2[6], eC3);
    }

    const float fbA = W[1560], fbB = W[1561], fbC = W[1562];
    const float sA0 = fbA + linA01.x + eA0.x + eA0.y;
    const float sA1 = fbA + linA01.y + eA1.x + eA1.y;
    const float sA2 = fbA + linA23.x + eA2.x + eA2.y;
    const float sA3 = fbA + linA23.y + eA3.x + eA3.y;
    const float sB0 = fbB + linB01.x + eB0.x + eB0.y;
    const float sB1 = fbB + linB01.y + eB1.x + eB1.y;
    const float sB2 = fbB + linB23.x + eB2.x + eB2.y;
    const float sB3 = fbB + linB23.y + eB3.x + eB3.y;
    const float sC0 = fbC + linC01.x + eC0.x + eC0.y;
    const float sC1 = fbC + linC01.y + eC1.x + eC1.y;
    const float sC2 = fbC + linC23.x + eC2.x + eC2.y;
    const float sC3 = fbC + linC23.y + eC3.x + eC3.y;

    // ---- stage 2: F(e) via piecewise-linear LUT ----
    const float invh = W[1565], nlo = W[1566];
    const float4* lut = (const float4*)(W + 1568);
    float2 rA0 = lut_eval(sA0, invh, nlo, lut);
    float2 rB0 = lut_eval(sB0, invh, nlo, lut);
    float2 rC0 = lut_eval(sC0, invh, nlo, lut);
    float2 rA1 = lut_eval(sA1, invh, nlo, lut);
    float2 rB1 = lut_eval(sB1, invh, nlo, lut);
    float2 rC1 = lut_eval(sC1, invh, nlo, lut);
    float2 rA2 = lut_eval(sA2, invh, nlo, lut);
    float2 rB2 = lut_eval(sB2, invh, nlo, lut);
    float2 rC2 = lut_eval(sC2, invh, nlo, lut);
    float2 rA3 = lut_eval(sA3, invh, nlo, lut);
    float2 rB3 = lut_eval(sB3, invh, nlo, lut);
    float2 rC3 = lut_eval(sC3, invh, nlo, lut);

    // 24 contiguous floats per thread -> 6x dwordx4
    float4* o4 = (float4*)(out + (size_t)gid * 24);
    o4[0] = make_float4(rA0.x, rA0.y, rB0.x, rB0.y);
    o4[1] = make_float4(rC0.x, rC0.y, rA1.x, rA1.y);
    o4[2] = make_float4(rB1.x, rB1.y, rC1.x, rC1.y);
    o4[3] = make_float4(rA2.x, rA2.y, rB2.x, rB2.y);
    o4[4] = make_float4(rC2.x, rC2.y, rA3.x, rA3.y);
    o4[5] = make_float4(rB3.x, rB3.y, rC3.x, rC3.y);
}

extern "C" void kernel_launch(void* const* d_in, const int* in_sizes, int n_in,
                              void* d_out, int out_size, void* d_ws, size_t ws_size,
                              hipStream_t stream) {
    const float* x    = (const float*)d_in[0];
    const int*   perm = (const int*)d_in[1];
    float* W = (float*)d_ws;

    enc_prep<<<LUTN / 256, 256, 0, stream>>>(
        (const float*)d_in[2],  (const float*)d_in[3],  (const float*)d_in[4],
        (const float*)d_in[5],  (const float*)d_in[6],  (const float*)d_in[7],
        (const float*)d_in[8],  (const float*)d_in[9],  (const float*)d_in[10],
        (const float*)d_in[11], (const float*)d_in[12], (const float*)d_in[13],
        (const float*)d_in[14], (const float*)d_in[15], (const float*)d_in[16],
        (const float*)d_in[17], (const float*)d_in[18], (const float*)d_in[19],
        (const float*)d_in[20], (const float*)d_in[21],
        (const float*)d_in[22], (const float*)d_in[23],
        (const float*)d_in[24], (const float*)d_in[25],
        (const float*)d_in[26], (const float*)d_in[27], (const float*)d_in[28],
        (const float*)d_in[29], (const float*)d_in[30], (const float*)d_in[31],
        (const float*)d_in[32], (const float*)d_in[33], (const float*)d_in[34],
        (const float*)d_in[35], (const float*)d_in[36], (const float*)d_in[37],
        W);

    enc_main<<<(BATCH * LL) / 1024, 256, 0, stream>>>(x, perm, W, (float*)d_out);
}

// Round 11
// 36.695 us; speedup vs baseline: 1.0655x; 1.0655x over previous
//
#include <hip/hip_runtime.h>
#include <math.h>

// Problem constants (from reference)
#define BATCH 128
#define LL    4096
#define DIM   64
#define EPS   1e-3f
#define LUTN  2048

#define LOG2E 1.44269504088896340736f
#define LN2   0.69314718055994530942f

// Taylor coefficients of s(z) = (exp2(z)-1-ln2*z)/z^2  (z in [-1, 0])
#define GC2 0.2402265069591007f     // ln2^2/2
#define GC3 0.05550410866482158f    // ln2^3/6
#define GC4 0.009618129107628477f   // ln2^4/24
#define GC5 0.0013333558146428443f  // ln2^5/120

// d_ws layout (floats):
//  [0    .. 1536) : T[j][48], j = channel-pair 0..31; per j, br = 0..2 at f32x2
//                   offset br*8: {T0',..,T4', B', Fw, pad}. T' = 2*tap
//                   (log2e-scaled), B' = bias - sum(tap)  (2x-1 folded).
//  [1536 .. 1560) : LIN[3][8] = {L0..L4, Lb, pad, pad} per branch, folded:
//                   Lk = 2*ln2*r_k, Lb = ln2*(rb - sum r_k)
//  [1560 .. 1563) : FB[3]  = f_b
//  [1563 .. 1565) : D0, D1
//  [1565]         : invh ; [1566] : nlo ; [1567] : lo
//  [1568 .. 1568+4*LUTN) : LUT float4 {F0(e_i), F1(e_i), dF0_i, dF1_i}

typedef float f32x2 __attribute__((ext_vector_type(2)));

__device__ __forceinline__ f32x2 pk_fma(f32x2 a, f32x2 b, f32x2 c) {
    return __builtin_elementwise_fma(a, b, c);
}

__device__ __forceinline__ float elu_plain(float z) {
    return z > 0.0f ? z : (__expf(z) - 1.0f);
}

// ONE prologue kernel, 8 blocks x 256 threads.
__global__ __launch_bounds__(256) void enc_prep(
    const float* __restrict__ cw0, const float* __restrict__ cb0, const float* __restrict__ cg0,
    const float* __restrict__ cbe0, const float* __restrict__ cm0, const float* __restrict__ cv0,
    const float* __restrict__ cw1, const float* __restrict__ cb1, const float* __restrict__ cg1,
    const float* __restrict__ cbe1, const float* __restrict__ cm1, const float* __restrict__ cv1,
    const float* __restrict__ cw2, const float* __restrict__ cb2, const float* __restrict__ cg2,
    const float* __restrict__ cbe2, const float* __restrict__ cm2, const float* __restrict__ cv2,
    const float* __restrict__ f0w, const float* __restrict__ f0b,
    const float* __restrict__ f1w, const float* __restrict__ f1b,
    const float* __restrict__ f2w, const float* __restrict__ f2b,
    const float* __restrict__ mpw, const float* __restrict__ mpb, const float* __restrict__ mpg,
    const float* __restrict__ mpbe, const float* __restrict__ mpm, const float* __restrict__ mpv,
    const float* __restrict__ mdw, const float* __restrict__ mdb, const float* __restrict__ mdg,
    const float* __restrict__ mdbe, const float* __restrict__ mdm, const float* __restrict__ mdv,
    float* __restrict__ W)
{
    const int t   = threadIdx.x;
    const int blk = blockIdx.x;
    __shared__ float smod[64][4];          // {A, C, m0, m1}
    __shared__ float s_lo[3], s_hi[3];
    __shared__ float sD[2];
    __shared__ float srange[2];            // lo, hstep

    if (t < 192) {
        const int br = t >> 6;             // wave-aligned: wave 0,1,2 = branch 0,1,2
        const int d  = t & 63;
        const float* cw  = (br == 0) ? cw0  : (br == 1) ? cw1  : cw2;
        const float* cb  = (br == 0) ? cb0  : (br == 1) ? cb1  : cb2;
        const float* cg  = (br == 0) ? cg0  : (br == 1) ? cg1  : cg2;
        const float* cbe = (br == 0) ? cbe0 : (br == 1) ? cbe1 : cbe2;
        const float* cm  = (br == 0) ? cm0  : (br == 1) ? cm1  : cm2;
        const float* cv  = (br == 0) ? cv0  : (br == 1) ? cv1  : cv2;
        const float* fw  = (br == 0) ? f0w  : (br == 1) ? f1w  : f2w;
        const float s = cg[d] / sqrtf(cv[d] + EPS);
        float tap[5], habs = 0.0f, tsum = 0.0f;
        #pragma unroll
        for (int k = 0; k < 5; ++k) {
            tap[k] = cw[k * 64 + d] * s * LOG2E;
            habs += fabsf(tap[k]);
            tsum += tap[k];
        }
        const float bias = ((cb[d] - cm[d]) * s + cbe[d]) * LOG2E;
        const float fwd  = fw[d];
        if (blk == 0) {
            // f32x2 layout: j*24 + br*8 + {0..4 taps, 5 bias, 6 fw, 7 pad}
            float* o = W + ((d >> 1) * 24 + br * 8) * 2 + (d & 1);
            o[0] = 2.0f * tap[0]; o[2] = 2.0f * tap[1]; o[4] = 2.0f * tap[2];
            o[6] = 2.0f * tap[3]; o[8] = 2.0f * tap[4];
            o[10] = bias - tsum;           // (2x-1) folded
            o[12] = fwd;
        }
        const float hb = LN2 * (habs + fabsf(bias));   // bound on |h_real|, |x~|<=1
        // reductions over the 64-lane branch wave:
        float r0 = fwd * tap[0], r1 = fwd * tap[1], r2 = fwd * tap[2];
        float r3 = fwd * tap[3], r4 = fwd * tap[4], rb = fwd * bias;
        float myS = fabsf(fwd) * fmaxf(1.0f, hb);      // |fw * elu(h)| bound
        #pragma unroll
        for (int off = 32; off; off >>= 1) {
            r0 += __shfl_down(r0, off);
            r1 += __shfl_down(r1, off);
            r2 += __shfl_down(r2, off);
            r3 += __shfl_down(r3, off);
            r4 += __shfl_down(r4, off);
            rb += __shfl_down(rb, off);
            myS += __shfl_down(myS, off);
        }
        if ((t & 63) == 0) {
            const float fb = ((br == 0) ? f0b : (br == 1) ? f1b : f2b)[0];
            s_lo[br] = fb - myS;
            s_hi[br] = fb + myS;
            if (blk == 0) {
                float* Lb = W + 1536 + br * 8;
                const float rs = r0 + r1 + r2 + r3 + r4;
                Lb[0] = 2.0f * LN2 * r0; Lb[1] = 2.0f * LN2 * r1;
                Lb[2] = 2.0f * LN2 * r2; Lb[3] = 2.0f * LN2 * r3;
                Lb[4] = 2.0f * LN2 * r4;
                Lb[5] = LN2 * (rb - rs);   // (2x-1) folded
                W[1560 + br] = fb;
            }
        }
    } else {
        const int d = t - 192;
        const float smp = mpg[d] / sqrtf(mpv[d] + EPS);
        const float A = mpw[d] * smp;
        const float C = (mpb[d] - mpm[d]) * smp + mpbe[d];
        const float s0 = mdg[0] / sqrtf(mdv[0] + EPS);
        const float s1 = mdg[1] / sqrtf(mdv[1] + EPS);
        smod[d][0] = A;
        smod[d][1] = C;
        smod[d][2] = mdw[d * 2 + 0] * s0;
        smod[d][3] = mdw[d * 2 + 1] * s1;
        if (d == 0) {
            const float D0 = (mdb[0] - mdm[0]) * s0 + mdbe[0];
            const float D1 = (mdb[1] - mdm[1]) * s1 + mdbe[1];
            sD[0] = D0; sD[1] = D1;
            if (blk == 0) { W[1563] = D0; W[1564] = D1; }
        }
    }
    __syncthreads();

    if (t == 0) {
        float lo = fminf(s_lo[0], fminf(s_lo[1], s_lo[2]));
        float hi = fmaxf(s_hi[0], fmaxf(s_hi[1], s_hi[2]));
        float pad = 1e-3f * (hi - lo) + 1e-6f;
        lo -= pad; hi += pad;
        srange[0] = lo;
        srange[1] = (hi - lo) / (float)(LUTN - 1);
        if (blk == 0) {
            const float invh = (float)(LUTN - 1) / (hi - lo);
            W[1565] = invh;
            W[1566] = -lo * invh;
            W[1567] = lo;
        }
    }
    __syncthreads();

    // LUT slice: entry i for this thread
    const int i = blk * 256 + t;
    const float lo = srange[0], hs = srange[1];
    const float D0 = sD[0], D1 = sD[1];
    const float e0 = fmaf((float)i, hs, lo);
    const float e1 = fmaf((float)(i + 1), hs, lo);
    float a0 = D0, a1 = D1, b0 = D0, b1 = D1;
    #pragma unroll 8
    for (int d = 0; d < 64; ++d) {
        const float A = smod[d][0], C = smod[d][1], m0 = smod[d][2], m1 = smod[d][3];
        float u;
        u = elu_plain(fmaf(A, e0, C)); a0 = fmaf(m0, u, a0); a1 = fmaf(m1, u, a1);
        u = elu_plain(fmaf(A, e1, C)); b0 = fmaf(m0, u, b0); b1 = fmaf(m1, u, b1);
    }
    float4* lut = (float4*)(W + 1568);
    lut[i] = make_float4(a0, a1, b0 - a0, b1 - a1);
}

__device__ __forceinline__ float2 lut_eval(float e, float invh, float nlo,
                                           const float4* __restrict__ lut) {
    float tt = fminf(fmaxf(fmaf(e, invh, nlo), 0.0f), (float)(LUTN - 1));
    float fi = floorf(tt); float f = tt - fi;
    float4 v = lut[(int)fi];
    return make_float2(fmaf(f, v.z, v.x), fmaf(f, v.w, v.y));
}

// nonlinear elu remainder: fw * z^2 * s(z), z = min(h',0), deg-3 Taylor tail,
// GC constants live in registers (not the weight stream)
__device__ __forceinline__ void nl_acc(f32x2 h, f32x2 fw, f32x2& e) {
    const f32x2 zero = {0.0f, 0.0f};
    f32x2 z  = __builtin_elementwise_min(h, zero);
    f32x2 zz = z * z;
    f32x2 s  = pk_fma(z, f32x2{GC5, GC5}, f32x2{GC4, GC4});
    s = pk_fma(z, s, f32x2{GC3, GC3});
    s = pk_fma(z, s, f32x2{GC2, GC2});
    e = pk_fma(fw, zz * s, e);
}

// 1024 blocks x 256 threads; 2 positions/thread, channel-pair packed f32 math.
// Linear part collapsed into one 5-tap filter per branch; 2x-1 folded.
__global__ __launch_bounds__(256) void enc_main(
    const float* __restrict__ x, const int* __restrict__ perm,
    const float* __restrict__ W, float* __restrict__ out)
{
    const int gid = blockIdx.x * 256 + threadIdx.x;   // position-pair index
    const int b   = gid >> 11;
    const int l0  = (gid & (2048 - 1)) * 2;
    const float* xrow = x + ((size_t)b << 12);
    const int*   prow = perm + ((size_t)b << 12);

    // 6-wide circular windows via 8B vector loads (bases even, no intra-pair wrap)
    const int ba = (l0 - 2) & (LL - 1);
    const int bc = (l0 + 2) & (LL - 1);
    const float2 w01 = *(const float2*)(xrow + ba);
    const float2 w23 = *(const float2*)(xrow + l0);
    const float2 w45 = *(const float2*)(xrow + bc);
    const int2 p01 = *(const int2*)(prow + ba);
    const int2 p23 = *(const int2*)(prow + l0);
    const int2 p45 = *(const int2*)(prow + bc);

    float xw[6], xg[6];
    xw[0] = w01.x; xw[1] = w01.y; xw[2] = w23.x;
    xw[3] = w23.y; xw[4] = w45.x; xw[5] = w45.y;
    xg[0] = xrow[p01.x]; xg[1] = xrow[p01.y];
    xg[2] = xrow[p23.x]; xg[3] = xrow[p23.y];
    xg[4] = xrow[p45.x]; xg[5] = xrow[p45.y];

    // channel-pair packing: both halves carry the same x value
    f32x2 xs[6], xi[6];
    #pragma unroll
    for (int k = 0; k < 6; ++k) {
        xs[k] = f32x2{xw[k], xw[k]};
        xi[k] = f32x2{xg[k], xg[k]};
    }

    // collapsed linear part per (branch, pos) — folded weights, raw x
    const float* LA = W + 1536;
    const float* LB = W + 1544;
    const float* LC = W + 1552;
    float linA0 = fmaf(LA[0], xw[0], fmaf(LA[1], xw[1], fmaf(LA[2], xw[2],
                  fmaf(LA[3], xw[3], fmaf(LA[4], xw[4], LA[5])))));
    float linA1 = fmaf(LA[0], xw[1], fmaf(LA[1], xw[2], fmaf(LA[2], xw[3],
                  fmaf(LA[3], xw[4], fmaf(LA[4], xw[5], LA[5])))));
    float linB0 = fmaf(LB[0], xw[0], fmaf(LB[1], xw[1], fmaf(LB[2], xw[2],
                  fmaf(LB[3], xw[3], fmaf(LB[4], xw[4], LB[5])))));
    float linB1 = fmaf(LB[0], xw[1], fmaf(LB[1], xw[2], fmaf(LB[2], xw[3],
                  fmaf(LB[3], xw[4], fmaf(LB[4], xw[5], LB[5])))));
    float linC0 = fmaf(LC[0], xg[0], fmaf(LC[1], xg[1], fmaf(LC[2], xg[2],
                  fmaf(LC[3], xg[3], fmaf(LC[4], xg[4], LC[5])))));
    float linC1 = fmaf(LC[0], xg[1], fmaf(LC[1], xg[2], fmaf(LC[2], xg[3],
                  fmaf(LC[3], xg[4], fmaf(LC[4], xg[5], LC[5])))));

    // nonlinear accumulators: [branch][pos], f32x2 over the channel pair
    f32x2 eA0 = {0.0f, 0.0f}, eA1 = {0.0f, 0.0f};
    f32x2 eB0 = {0.0f, 0.0f}, eB1 = {0.0f, 0.0f};
    f32x2 eC0 = {0.0f, 0.0f}, eC1 = {0.0f, 0.0f};

    #pragma unroll 4
    for (int j = 0; j < 32; ++j) {
        const f32x2* tp = (const f32x2*)W + j * 24;
        f32x2 h;

        // branch 0 (systematic): taps tp[0..4], bias tp[5], fw tp[6]
        h = pk_fma(tp[0], xs[0], pk_fma(tp[1], xs[1], pk_fma(tp[2], xs[2],
            pk_fma(tp[3], xs[3], pk_fma(tp[4], xs[4], tp[5])))));
        nl_acc(h, tp[6], eA0);
        h = pk_fma(tp[0], xs[1], pk_fma(tp[1], xs[2], pk_fma(tp[2], xs[3],
            pk_fma(tp[3], xs[4], pk_fma(tp[4], xs[5], tp[5])))));
        nl_acc(h, tp[6], eA1);

        // branch 1 (systematic): tp[8..12], tp[13], tp[14]
        h = pk_fma(tp[8], xs[0], pk_fma(tp[9], xs[1], pk_fma(tp[10], xs[2],
            pk_fma(tp[11], xs[3], pk_fma(tp[12], xs[4], tp[13])))));
        nl_acc(h, tp[14], eB0);
        h = pk_fma(tp[8], xs[1], pk_fma(tp[9], xs[2], pk_fma(tp[10], xs[3],
            pk_fma(tp[11], xs[4], pk_fma(tp[12], xs[5], tp[13])))));
        nl_acc(h, tp[14], eB1);

        // branch 2 (interleaved): tp[16..20], tp[21], tp[22]
        h = pk_fma(tp[16], xi[0], pk_fma(tp[17], xi[1], pk_fma(tp[18], xi[2],
            pk_fma(tp[19], xi[3], pk_fma(tp[20], xi[4], tp[21])))));
        nl_acc(h, tp[22], eC0);
        h = pk_fma(tp[16], xi[1], pk_fma(tp[17], xi[2], pk_fma(tp[18], xi[3],
            pk_fma(tp[19], xi[4], pk_fma(tp[20], xi[5], tp[21])))));
        nl_acc(h, tp[22], eC1);
    }

    const float fbA = W[1560], fbB = W[1561], fbC = W[1562];
    const float sA0 = fbA + linA0 + eA0.x + eA0.y;
    const float sA1 = fbA + linA1 + eA1.x + eA1.y;
    const float sB0 = fbB + linB0 + eB0.x + eB0.y;
    const float sB1 = fbB + linB1 + eB1.x + eB1.y;
    const float sC0 = fbC + linC0 + eC0.x + eC0.y;
    const float sC1 = fbC + linC1 + eC1.x + eC1.y;

    // ---- stage 2: F(e) via piecewise-linear LUT ----
    const float invh = W[1565], nlo = W[1566];
    const float4* lut = (const float4*)(W + 1568);
    float2 r0 = lut_eval(sA0, invh, nlo, lut);
    float2 r1 = lut_eval(sB0, invh, nlo, lut);
    float2 r2 = lut_eval(sC0, invh, nlo, lut);
    float2 r3 = lut_eval(sA1, invh, nlo, lut);
    float2 r4 = lut_eval(sB1, invh, nlo, lut);
    float2 r5 = lut_eval(sC1, invh, nlo, lut);

    // 12 contiguous floats per thread -> 3x dwordx4
    float4* o4 = (float4*)(out + (size_t)gid * 12);
    o4[0] = make_float4(r0.x, r0.y, r1.x, r1.y);
    o4[1] = make_float4(r2.x, r2.y, r3.x, r3.y);
    o4[2] = make_float4(r4.x, r4.y, r5.x, r5.y);
}

extern "C" void kernel_launch(void* const* d_in, const int* in_sizes, int n_in,
                              void* d_out, int out_size, void* d_ws, size_t ws_size,
                              hipStream_t stream) {
    const float* x    = (const float*)d_in[0];
    const int*   perm = (const int*)d_in[1];
    float* W = (float*)d_ws;

    enc_prep<<<LUTN / 256, 256, 0, stream>>>(
        (const float*)d_in[2],  (const float*)d_in[3],  (const float*)d_in[4],
        (const float*)d_in[5],  (const float*)d_in[6],  (const float*)d_in[7],
        (const float*)d_in[8],  (const float*)d_in[9],  (const float*)d_in[10],
        (const float*)d_in[11], (const float*)d_in[12], (const float*)d_in[13],
        (const float*)d_in[14], (const float*)d_in[15], (const float*)d_in[16],
        (const float*)d_in[17], (const float*)d_in[18], (const float*)d_in[19],
        (const float*)d_in[20], (const float*)d_in[21],
        (const float*)d_in[22], (const float*)d_in[23],
        (const float*)d_in[24], (const float*)d_in[25],
        (const float*)d_in[26], (const float*)d_in[27], (const float*)d_in[28],
        (const float*)d_in[29], (const float*)d_in[30], (const float*)d_in[31],
        (const float*)d_in[32], (const float*)d_in[33], (const float*)d_in[34],
        (const float*)d_in[35], (const float*)d_in[36], (const float*)d_in[37],
        W);

    enc_main<<<(BATCH * LL) / 512, 256, 0, stream>>>(x, perm, W, (float*)d_out);
}